// Round 1
// baseline (5331.306 us; speedup 1.0000x reference)
//
#include <hip/hip_runtime.h>
#include <math.h>

// Problem constants
constexpr int NB  = 256;   // batch
constexpr int NS  = 8;     // seq / nodes
constexpr int NC  = 8;     // channels
constexpr int NH  = 501;   // hidden
constexpr int NL  = 56;    // latent
constexpr int NH2 = 1002;
constexpr int NH3 = 1503;
constexpr int NH4 = 2004;
constexpr int NTOT = NH4 + 2*NH;  // 3006 rows in phase-A GEMM

__device__ __forceinline__ float sigf(float x) { return 1.0f / (1.0f + __expf(-x)); }

__global__ __launch_bounds__(256) void kZero(float* __restrict__ p, int n) {
  int i = blockIdx.x * 256 + threadIdx.x;
  if (i < n) p[i] = 0.0f;
}

// graph_state0 = z @ lin1_w.T + lin1_b   -> hv (feature-major: hv[h*NB+b])
__global__ __launch_bounds__(256) void kLin1(const float* __restrict__ z,
                                             const float* __restrict__ w,
                                             const float* __restrict__ bias,
                                             float* __restrict__ hv) {
  int h = blockIdx.x, b = threadIdx.x;
  const float* wr = w + (size_t)h * NL;
  const float* zr = z + (size_t)b * NL;
  float acc = bias[h];
#pragma unroll
  for (int l = 0; l < NL; ++l) acc += zr[l] * wr[l];
  hv[h * NB + b] = acc;
}

// Phase A / cache GEMM: 3006 output rows from src (NH x NB feature-major).
// rows [0,2004): ae_w1 row m, cols [colOff, colOff+501)
// rows [2004,2505): gate_w ; rows [2505,3006): map_w
// doRelu=1 (inner): edge rows get + Rj + ae_b1, relu -> oe ; P/Q raw -> oP/oQ
// doRelu=0 (cache): raw accumulations -> oe(=R slot), oP(=P slot), oQ(=Q slot)
__global__ __launch_bounds__(256) void kA(const float* __restrict__ src,
                                          const float* __restrict__ ae_w1,
                                          const float* __restrict__ gate_w,
                                          const float* __restrict__ map_w,
                                          const float* __restrict__ ae_b1,
                                          const float* __restrict__ Rj,
                                          float* __restrict__ oe,
                                          float* __restrict__ oP,
                                          float* __restrict__ oQ,
                                          int colOff, int doRelu) {
  int b = threadIdx.x;
  int m0 = blockIdx.x * 8;
  const float* w[8];
#pragma unroll
  for (int mi = 0; mi < 8; ++mi) {
    int m = m0 + mi;
    const float* p;
    if (m < NH4)           p = ae_w1 + (size_t)m * NH2 + colOff;
    else if (m < NH4 + NH) p = gate_w + (size_t)(m - NH4) * NH;
    else if (m < NTOT)     p = map_w + (size_t)(m - NH4 - NH) * NH;
    else                   p = gate_w;  // dummy, store skipped
    w[mi] = p;
  }
  float acc[8] = {};
  int k = 0;
  for (; k + 8 <= NH; k += 8) {
    float v[8];
#pragma unroll
    for (int kk = 0; kk < 8; ++kk) v[kk] = src[(k + kk) * NB + b];
#pragma unroll
    for (int mi = 0; mi < 8; ++mi) {
#pragma unroll
      for (int kk = 0; kk < 8; ++kk) acc[mi] += w[mi][k + kk] * v[kk];
    }
  }
  for (; k < NH; ++k) {
    float v = src[k * NB + b];
#pragma unroll
    for (int mi = 0; mi < 8; ++mi) acc[mi] += w[mi][k] * v;
  }
#pragma unroll
  for (int mi = 0; mi < 8; ++mi) {
    int m = m0 + mi;
    if (m >= NTOT) break;
    if (m < NH4) {
      if (doRelu) {
        float vv = acc[mi] + Rj[m * NB + b] + ae_b1[m];
        oe[m * NB + b] = vv > 0.f ? vv : 0.f;
      } else {
        oe[m * NB + b] = acc[mi];
      }
    } else if (m < NH4 + NH) {
      oP[(m - NH4) * NB + b] = acc[mi];
    } else {
      oQ[(m - NH4 - NH) * NB + b] = acc[mi];
    }
  }
}

// t1 = relu(src @ av_w1.T + av_b1)   (1002 rows)
__global__ __launch_bounds__(256) void kLog1(const float* __restrict__ src,
                                             const float* __restrict__ av_w1,
                                             const float* __restrict__ av_b1,
                                             float* __restrict__ t1) {
  int b = threadIdx.x;
  int m0 = blockIdx.x * 8;
  const float* w[8];
#pragma unroll
  for (int mi = 0; mi < 8; ++mi) {
    int m = m0 + mi;
    w[mi] = av_w1 + (size_t)(m < NH2 ? m : (NH2 - 1)) * NH;
  }
  float acc[8] = {};
  int k = 0;
  for (; k + 8 <= NH; k += 8) {
    float v[8];
#pragma unroll
    for (int kk = 0; kk < 8; ++kk) v[kk] = src[(k + kk) * NB + b];
#pragma unroll
    for (int mi = 0; mi < 8; ++mi) {
#pragma unroll
      for (int kk = 0; kk < 8; ++kk) acc[mi] += w[mi][k + kk] * v[kk];
    }
  }
  for (; k < NH; ++k) {
    float v = src[k * NB + b];
#pragma unroll
    for (int mi = 0; mi < 8; ++mi) acc[mi] += w[mi][k] * v;
  }
#pragma unroll
  for (int mi = 0; mi < 8; ++mi) {
    int m = m0 + mi;
    if (m < NH2) {
      float vv = acc[mi] + av_b1[m];
      t1[m * NB + b] = vv > 0.f ? vv : 0.f;
    }
  }
}

// logits = softmax(t1 @ av_w2.T + av_b2) -> out1[b][index][c]
__global__ __launch_bounds__(256) void kLog2(const float* __restrict__ t1,
                                             const float* __restrict__ av_w2,
                                             const float* __restrict__ av_b2,
                                             float* __restrict__ out1,
                                             int index) {
  __shared__ float red[8][32][8];
  __shared__ float logit[32][9];
  int tid = threadIdx.x;
  int bl = tid & 31, mc = tid >> 5;
  int b = blockIdx.x * 32 + bl;
  float acc[8] = {};
  int m0 = mc * 126, m1 = min(m0 + 126, NH2);
  for (int m = m0; m < m1; ++m) {
    float v = t1[m * NB + b];
#pragma unroll
    for (int c = 0; c < 8; ++c) acc[c] += v * av_w2[c * NH2 + m];
  }
#pragma unroll
  for (int c = 0; c < 8; ++c) red[mc][bl][c] = acc[c];
  __syncthreads();
  int bl2 = tid >> 3, c2 = tid & 7;
  float s = av_b2[c2];
#pragma unroll
  for (int q = 0; q < 8; ++q) s += red[q][bl2][c2];
  logit[bl2][c2] = s;
  __syncthreads();
  float mx = -1e30f;
#pragma unroll
  for (int c = 0; c < 8; ++c) mx = fmaxf(mx, logit[bl2][c]);
  float den = 0.f;
#pragma unroll
  for (int c = 0; c < 8; ++c) den += __expf(logit[bl2][c] - mx);
  int bb = blockIdx.x * 32 + bl2;
  out1[(bb * NS + index) * NC + c2] = __expf(logit[bl2][c2] - mx) / den;
}

// gi = x @ gru_w_ih.T + gru_b_ih  (x = node_encoding[:,index]); also zeroes RS.
__global__ __launch_bounds__(256) void kGi(const float* __restrict__ ne,
                                           const float* __restrict__ w_ih,
                                           const float* __restrict__ b_ih,
                                           float* __restrict__ gi,
                                           float* __restrict__ RS,
                                           int index) {
  int blk = blockIdx.x, b = threadIdx.x;
  if (blk < NH3) {
    float acc = b_ih[blk];
#pragma unroll
    for (int c = 0; c < NC; ++c)
      acc += ne[b * (NS * NC) + index * NC + c] * w_ih[blk * NC + c];
    gi[blk * NB + b] = acc;
  } else {
    RS[(blk - NH3) * NB + b] = 0.f;
  }
}

// Assembly: RS += F_j ; h_in = RS + (useFi ? F_index(hv) : Kb) + cnt*Kb
// Extra blocks: edge partial reduction over act * ae_w2.
__global__ __launch_bounds__(256) void kAsm(const float* __restrict__ Pj,
                                            const float* __restrict__ Qj,
                                            const float* __restrict__ Phv,
                                            const float* __restrict__ Qhv,
                                            const float* __restrict__ gate_b,
                                            const float* __restrict__ map_b,
                                            const float* __restrict__ dep,
                                            float* __restrict__ RS,
                                            float* __restrict__ hin,
                                            const float* __restrict__ act,
                                            const float* __restrict__ ae_w2,
                                            float* __restrict__ par,
                                            int index, int j, int useFi) {
  int blk = blockIdx.x, b = threadIdx.x;
  if (blk < NH) {
    int h = blk;
    float dj = dep[b * (NS * NS) + index * NS + j];
    float di = dep[b * (NS * NS) + index * NS + index];
    float gb = gate_b[h], mb = map_b[h];
    float fj = sigf(dj * Pj[h * NB + b] + gb) * (dj * Qj[h * NB + b] + mb);
    float rs = RS[h * NB + b] + fj;
    RS[h * NB + b] = rs;
    float kb = sigf(gb) * mb;
    float fi = useFi ? (sigf(di * Phv[h * NB + b] + gb) * (di * Qhv[h * NB + b] + mb)) : kb;
    float cnt = (float)(7 - (index - j));
    hin[h * NB + b] = rs + fi + cnt * kb;
  } else {
    int p = blk - NH;  // 0..15
    int m0 = p * 126, m1 = min(m0 + 126, NH4);
    float s = 0.f;
    for (int m = m0; m < m1; ++m) s += act[m * NB + b] * ae_w2[m];
    par[p * NB + b] = s;
  }
}

// Phase B: gh = src @ gru_w_hh.T + b_hh (src may be null -> gh=b_hh),
// GRU combine with hid (may be null -> 0) -> dst. Block 251: edge finalize.
__global__ __launch_bounds__(256) void kB(const float* __restrict__ src,
                                          const float* __restrict__ hid,
                                          const float* __restrict__ gi,
                                          const float* __restrict__ w_hh,
                                          const float* __restrict__ b_hh,
                                          float* __restrict__ dst,
                                          const float* __restrict__ par,
                                          const float* __restrict__ ae_b2,
                                          float* __restrict__ out0,
                                          int index, int j) {
  int b = threadIdx.x;
  int bb = blockIdx.x;
  if (bb == 251) {
    if (out0 != nullptr) {
      float s = ae_b2[0];
#pragma unroll
      for (int p = 0; p < 16; ++p) s += par[p * NB + b];
      out0[(b * NS + index) * NS + j] = s;
    }
    return;
  }
  int h0 = bb * 2;
  int h1 = (h0 + 1 < NH) ? (h0 + 1) : (NH - 1);  // clamp; dup compute, guarded store
  float acc[2][3] = {};
  if (src != nullptr) {
    const float* w[2][3];
#pragma unroll
    for (int t = 0; t < 2; ++t) {
      int h = (t == 0) ? h0 : h1;
#pragma unroll
      for (int g = 0; g < 3; ++g) w[t][g] = w_hh + (size_t)(g * NH + h) * NH;
    }
    int k = 0;
    for (; k + 4 <= NH; k += 4) {
      float v0 = src[(k + 0) * NB + b];
      float v1 = src[(k + 1) * NB + b];
      float v2 = src[(k + 2) * NB + b];
      float v3 = src[(k + 3) * NB + b];
#pragma unroll
      for (int t = 0; t < 2; ++t)
#pragma unroll
        for (int g = 0; g < 3; ++g)
          acc[t][g] += w[t][g][k] * v0 + w[t][g][k + 1] * v1 + w[t][g][k + 2] * v2 + w[t][g][k + 3] * v3;
    }
    for (; k < NH; ++k) {
      float v = src[k * NB + b];
#pragma unroll
      for (int t = 0; t < 2; ++t)
#pragma unroll
        for (int g = 0; g < 3; ++g) acc[t][g] += w[t][g][k] * v;
    }
  }
#pragma unroll
  for (int t = 0; t < 2; ++t) {
    if (t == 1 && h0 + 1 >= NH) break;
    int h = (t == 0) ? h0 : h1;
    float hr = acc[t][0] + b_hh[h];
    float hz = acc[t][1] + b_hh[NH + h];
    float hn = acc[t][2] + b_hh[2 * NH + h];
    float ir = gi[h * NB + b];
    float iz = gi[(NH + h) * NB + b];
    float inn = gi[(2 * NH + h) * NB + b];
    float r = sigf(ir + hr);
    float zz = sigf(iz + hz);
    float n = tanhf(inn + r * hn);
    float hd = (hid != nullptr) ? hid[h * NB + b] : 0.f;
    dst[h * NB + b] = (1.f - zz) * n + zz * hd;
  }
}

extern "C" void kernel_launch(void* const* d_in, const int* in_sizes, int n_in,
                              void* d_out, int out_size, void* d_ws, size_t ws_size,
                              hipStream_t stream) {
  (void)in_sizes; (void)n_in; (void)out_size; (void)ws_size;
  const float* z      = (const float*)d_in[0];
  const float* dep    = (const float*)d_in[1];
  const float* ne     = (const float*)d_in[2];
  const float* lin1_w = (const float*)d_in[3];
  const float* lin1_b = (const float*)d_in[4];
  const float* av_w1  = (const float*)d_in[5];
  const float* av_b1  = (const float*)d_in[6];
  const float* av_w2  = (const float*)d_in[7];
  const float* av_b2  = (const float*)d_in[8];
  const float* ae_w1  = (const float*)d_in[9];
  const float* ae_b1  = (const float*)d_in[10];
  const float* ae_w2  = (const float*)d_in[11];
  const float* ae_b2  = (const float*)d_in[12];
  const float* gate_w = (const float*)d_in[13];
  const float* gate_b = (const float*)d_in[14];
  const float* map_w  = (const float*)d_in[15];
  const float* map_b  = (const float*)d_in[16];
  const float* w_ih   = (const float*)d_in[17];
  const float* w_hh   = (const float*)d_in[18];
  const float* b_ih   = (const float*)d_in[19];
  const float* b_hh   = (const float*)d_in[20];

  float* out0 = (float*)d_out;                 // gen_dep (B,S,S)
  float* out1 = out0 + NB * NS * NS;           // gen_enc (B,S,C)

  const int HB = NH * NB;
  float* ws  = (float*)d_ws;
  float* hvA = ws;                     ws += HB;
  float* hvB = ws;                     ws += HB;
  float* Pc  = ws;                     ws += NS * HB;
  float* Qc  = ws;                     ws += NS * HB;
  float* Rc  = ws;                     ws += (size_t)NS * NH4 * NB;
  float* act = ws;                     ws += NH4 * NB;
  float* Phv = ws;                     ws += HB;
  float* Qhv = ws;                     ws += HB;
  float* RS  = ws;                     ws += HB;
  float* hin = ws;                     ws += HB;
  float* gi  = ws;                     ws += NH3 * NB;
  float* t1  = ws;                     ws += NH2 * NB;
  float* par = ws;                     ws += 16 * NB;

  float* bufs[2] = {hvA, hvB};
  int cur = 0;

  kZero<<<64, 256, 0, stream>>>(out0, NB * NS * NS);
  kLin1<<<NH, 256, 0, stream>>>(z, lin1_w, lin1_b, hvA);

  const int gridA = (NTOT + 7) / 8;    // 376
  const int gridL1 = (NH2 + 7) / 8;    // 126

  for (int index = 0; index < NS; ++index) {
    // logits from current graph_state
    kLog1<<<gridL1, 256, 0, stream>>>(bufs[cur], av_w1, av_b1, t1);
    kLog2<<<8, 256, 0, stream>>>(t1, av_w2, av_b2, out1, index);
    // gi for this step + zero RS
    kGi<<<NH3 + NH, 256, 0, stream>>>(ne, w_ih, b_ih, gi, RS, index);
    // hv0 = gru(x, h0);  h0 = (index==0) ? graph_state : 0
    kB<<<252, 256, 0, stream>>>(index == 0 ? bufs[cur] : nullptr,
                                index == 0 ? bufs[cur] : nullptr,
                                gi, w_hh, b_hh, bufs[1 - cur],
                                nullptr, ae_b2, nullptr, index, 0);
    cur ^= 1;
    for (int j = index - 1; j >= 0; --j) {
      kA<<<gridA, 256, 0, stream>>>(bufs[cur], ae_w1, gate_w, map_w, ae_b1,
                                    Rc + (size_t)j * NH4 * NB,
                                    act, Phv, Qhv, /*colOff=*/0, /*doRelu=*/1);
      kAsm<<<NH + 16, 256, 0, stream>>>(Pc + (size_t)j * HB, Qc + (size_t)j * HB,
                                        Phv, Qhv, gate_b, map_b, dep,
                                        RS, hin, act, ae_w2, par,
                                        index, j, /*useFi=*/(j < index - 1) ? 1 : 0);
      kB<<<252, 256, 0, stream>>>(hin, hin, gi, w_hh, b_hh, bufs[1 - cur],
                                  par, ae_b2, out0, index, j);
      cur ^= 1;
    }
    // cache P/Q/R for finalized nhs[:,index] = hv
    kA<<<gridA, 256, 0, stream>>>(bufs[cur], ae_w1, gate_w, map_w, ae_b1,
                                  nullptr,
                                  Rc + (size_t)index * NH4 * NB,
                                  Pc + (size_t)index * HB,
                                  Qc + (size_t)index * HB,
                                  /*colOff=*/NH, /*doRelu=*/0);
  }
}

// Round 2
// 2153.961 us; speedup vs baseline: 2.4751x; 2.4751x over previous
//
#include <hip/hip_runtime.h>
#include <math.h>

constexpr int NB  = 256;
constexpr int NS  = 8;
constexpr int NC  = 8;
constexpr int NH  = 501;
constexpr int NL  = 56;
constexpr int NH2 = 1002;
constexpr int NH3 = 1503;
constexpr int NH4 = 2004;
constexpr int KP  = 512;          // padded K
constexpr int HB  = NH * NB;      // 128256
constexpr int HVSZ = KP * NB;     // 131072 padded activation buffer (rows 501..511 zero)

typedef _Float16 half8 __attribute__((ext_vector_type(8)));
typedef float f32x4 __attribute__((ext_vector_type(4)));

__device__ __forceinline__ float sigf(float x) { return 1.0f / (1.0f + __expf(-x)); }

// ---------------- init / pack kernels ----------------

__global__ __launch_bounds__(256) void kZero4(float4* __restrict__ p, int n4) {
  int i = blockIdx.x * 256 + threadIdx.x;
  if (i < n4) p[i] = make_float4(0.f, 0.f, 0.f, 0.f);
}

// zero pad rows 501..511 of hvA, hvB, hin
__global__ __launch_bounds__(256) void kPadZ(float* a, float* b, float* c) {
  int e = blockIdx.x * 256 + threadIdx.x;
  if (e >= 3 * 11 * NB) return;
  int which = e / (11 * NB);
  int rem = e % (11 * NB);
  float* p = which == 0 ? a : (which == 1 ? b : c);
  p[(NH + rem / NB) * NB + (rem % NB)] = 0.f;
}

// out0 init: ae_b2[0] where j<index else 0
__global__ __launch_bounds__(256) void kInit0(float* __restrict__ out0, const float* __restrict__ ae_b2) {
  int e = blockIdx.x * 256 + threadIdx.x;   // 16384
  int b = e >> 6, r = e & 63;
  int i = r >> 3, jj = r & 7;
  out0[b * 64 + i * 8 + jj] = (jj < i) ? ae_b2[0] : 0.f;
}

// fp32 pack: rows [0,1024): gate/map interleaved (2h,2h+1); [1024,2560): w_hh triples
// (1024+3h+{r,z,n}); [2560,3584): av_w1. K padded to 512 with zeros.
__global__ __launch_bounds__(256) void kPackF(const float* __restrict__ gate_w,
                                              const float* __restrict__ map_w,
                                              const float* __restrict__ w_hh,
                                              const float* __restrict__ av_w1,
                                              float* __restrict__ pack) {
  int r = blockIdx.x;
  for (int k = threadIdx.x; k < KP; k += 256) {
    float v = 0.f;
    if (k < NH) {
      if (r < 1024) {
        int h = r >> 1;
        if (h < NH) v = (r & 1) ? map_w[h * NH + k] : gate_w[h * NH + k];
      } else if (r < 2560) {
        int q = r - 1024; int h = q / 3, g = q % 3;
        if (h < NH) v = w_hh[((size_t)(g * NH + h)) * NH + k];
      } else {
        int m = r - 2560;
        if (m < NH2) v = av_w1[(size_t)m * NH + k];
      }
    }
    pack[(size_t)r * KP + k] = v;
  }
}

// fp16 packs of ae_w1 halves: Wl[m][k]=ae_w1[m][k], Wr[m][k]=ae_w1[m][501+k]; 2048 rows
__global__ __launch_bounds__(256) void kPackH(const float* __restrict__ ae_w1,
                                              _Float16* __restrict__ Wl,
                                              _Float16* __restrict__ Wr) {
  int m = blockIdx.x;
  for (int k = threadIdx.x; k < KP; k += 256) {
    float vl = 0.f, vr = 0.f;
    if (m < NH4 && k < NH) {
      vl = ae_w1[(size_t)m * NH2 + k];
      vr = ae_w1[(size_t)m * NH2 + NH + k];
    }
    Wl[(size_t)m * KP + k] = (_Float16)vl;
    Wr[(size_t)m * KP + k] = (_Float16)vr;
  }
}

// ---------------- small fp32 kernels ----------------

__global__ __launch_bounds__(256) void kLin1(const float* __restrict__ z,
                                             const float* __restrict__ w,
                                             const float* __restrict__ bias,
                                             float* __restrict__ hv) {
  int h = blockIdx.x, b = threadIdx.x;
  const float* wr = w + (size_t)h * NL;
  const float* zr = z + (size_t)b * NL;
  float acc = bias[h];
#pragma unroll
  for (int l = 0; l < NL; ++l) acc += zr[l] * wr[l];
  hv[h * NB + b] = acc;
}

__global__ __launch_bounds__(256) void kGi(const float* __restrict__ ne,
                                           const float* __restrict__ w_ih,
                                           const float* __restrict__ b_ih,
                                           float* __restrict__ gi,
                                           float* __restrict__ RS,
                                           int index) {
  int blk = blockIdx.x, b = threadIdx.x;
  if (blk < NH3) {
    float acc = b_ih[blk];
#pragma unroll
    for (int c = 0; c < NC; ++c)
      acc += ne[b * (NS * NC) + index * NC + c] * w_ih[blk * NC + c];
    gi[blk * NB + b] = acc;
  } else {
    RS[(blk - NH3) * NB + b] = 0.f;
  }
}

// hv0 for index>=1:  gru(x, 0) with gh = b_hh only; writes fp16 snapshot (edge input)
__global__ __launch_bounds__(256) void kB0(const float* __restrict__ gi,
                                           const float* __restrict__ b_hh,
                                           float* __restrict__ dst,
                                           _Float16* __restrict__ snapXe) {
  int h = blockIdx.x, b = threadIdx.x;
  float r = sigf(gi[h * NB + b] + b_hh[h]);
  float zz = sigf(gi[(NH + h) * NB + b] + b_hh[NH + h]);
  float n = tanhf(gi[(2 * NH + h) * NB + b] + r * b_hh[2 * NH + h]);
  float v = (1.f - zz) * n;
  dst[h * NB + b] = v;
  snapXe[(size_t)b * KP + h] = (_Float16)v;
}

// inner step j == index-1 (no fresh gate/map needed): RS += F_j (cached); hin
__global__ __launch_bounds__(256) void kAsmLite(const float* __restrict__ Pcj,
                                                const float* __restrict__ Qcj,
                                                const float* __restrict__ gate_b,
                                                const float* __restrict__ map_b,
                                                const float* __restrict__ dep,
                                                float* __restrict__ RS,
                                                float* __restrict__ hin,
                                                int index, int j) {
  int h = blockIdx.x, b = threadIdx.x;
  float dj = dep[b * 64 + index * 8 + j];
  float gb = gate_b[h], mb = map_b[h];
  float fj = sigf(dj * Pcj[h * NB + b] + gb) * (dj * Qcj[h * NB + b] + mb);
  float rs = RS[h * NB + b] + fj;
  RS[h * NB + b] = rs;
  float kb = sigf(gb) * mb;
  hin[h * NB + b] = rs + kb + (float)(7 - (index - j)) * kb;
}

// logits part 2 (unchanged from R1)
__global__ __launch_bounds__(256) void kLog2(const float* __restrict__ t1,
                                             const float* __restrict__ av_w2,
                                             const float* __restrict__ av_b2,
                                             float* __restrict__ out1,
                                             int index) {
  __shared__ float red[8][32][8];
  __shared__ float logit[32][9];
  int tid = threadIdx.x;
  int bl = tid & 31, mc = tid >> 5;
  int b = blockIdx.x * 32 + bl;
  float acc[8] = {};
  int m0 = mc * 126, m1 = min(m0 + 126, NH2);
  for (int m = m0; m < m1; ++m) {
    float v = t1[m * NB + b];
#pragma unroll
    for (int c = 0; c < 8; ++c) acc[c] += v * av_w2[c * NH2 + m];
  }
#pragma unroll
  for (int c = 0; c < 8; ++c) red[mc][bl][c] = acc[c];
  __syncthreads();
  int bl2 = tid >> 3, c2 = tid & 7;
  float s = av_b2[c2];
#pragma unroll
  for (int q = 0; q < 8; ++q) s += red[q][bl2][c2];
  logit[bl2][c2] = s;
  __syncthreads();
  float mx = -1e30f;
#pragma unroll
  for (int c = 0; c < 8; ++c) mx = fmaxf(mx, logit[bl2][c]);
  float den = 0.f;
#pragma unroll
  for (int c = 0; c < 8; ++c) den += __expf(logit[bl2][c] - mx);
  int bb = blockIdx.x * 32 + bl2;
  out1[(bb * NS + index) * NC + c2] = __expf(logit[bl2][c2] - mx) / den;
}

// ---------------- tiled fp32 GEMMs ----------------
// kGemm2: 32 rows (16 pairs) x 64 cols per block. modes: 0=GM(hin) 1=PQ 2=T1
__global__ __launch_bounds__(256) void kGemm2(
    const float* __restrict__ pack, int rowBase,
    const float* __restrict__ src, int mode, int index, int j,
    const float* __restrict__ dep, const float* __restrict__ gate_b,
    const float* __restrict__ map_b,
    const float* __restrict__ Pcj, const float* __restrict__ Qcj,
    float* __restrict__ RS, float* __restrict__ hin,
    float* __restrict__ PcO, float* __restrict__ QcO,
    float* __restrict__ t1o, const float* __restrict__ av_b1) {
  __shared__ float Ws[16][32];
  __shared__ float Xs[16][64];
  int t = threadIdx.x;
  int tb = t & 15, tm = t >> 4;
  int mT = blockIdx.x, nB0 = blockIdx.y * 64;
  bool wact = t < 128;
  const float* wsrc = pack + (size_t)(rowBase + mT * 32 + (t >> 2)) * KP + (t & 3) * 4;
  const float* xsrc = src + (size_t)(t >> 4) * NB + nB0 + (t & 15) * 4;
  float4 wv = make_float4(0, 0, 0, 0), xv;
  if (wact) wv = *(const float4*)(wsrc);
  xv = *(const float4*)(xsrc);
  float acc0[4] = {}, acc1[4] = {};
  for (int ch = 0; ch < 32; ++ch) {
    if (wact) {
      int r = t >> 2, kq = (t & 3) * 4;
      Ws[kq + 0][r] = wv.x; Ws[kq + 1][r] = wv.y; Ws[kq + 2][r] = wv.z; Ws[kq + 3][r] = wv.w;
    }
    *(float4*)&Xs[t >> 4][(t & 15) * 4] = xv;
    __syncthreads();
    if (ch + 1 < 32) {
      if (wact) wv = *(const float4*)(wsrc + (ch + 1) * 16);
      xv = *(const float4*)(xsrc + (size_t)(ch + 1) * 16 * NB);
    }
#pragma unroll
    for (int kk = 0; kk < 16; ++kk) {
      float w0 = Ws[kk][tm * 2], w1 = Ws[kk][tm * 2 + 1];
      float x0 = Xs[kk][tb * 4], x1 = Xs[kk][tb * 4 + 1];
      float x2 = Xs[kk][tb * 4 + 2], x3 = Xs[kk][tb * 4 + 3];
      acc0[0] += w0 * x0; acc0[1] += w0 * x1; acc0[2] += w0 * x2; acc0[3] += w0 * x3;
      acc1[0] += w1 * x0; acc1[1] += w1 * x1; acc1[2] += w1 * x2; acc1[3] += w1 * x3;
    }
    __syncthreads();
  }
  if (mode == 0) {
    int h = mT * 16 + tm;
    if (h < NH) {
      float gb = gate_b[h], mb = map_b[h];
      float kb = sigf(gb) * mb;
      float cnt = (float)(7 - (index - j));
#pragma unroll
      for (int bi = 0; bi < 4; ++bi) {
        int b = nB0 + tb * 4 + bi;
        float dj = dep[b * 64 + index * 8 + j];
        float di = dep[b * 64 + index * 8 + index];
        float fj = sigf(dj * Pcj[h * NB + b] + gb) * (dj * Qcj[h * NB + b] + mb);
        float rs = RS[h * NB + b] + fj;
        RS[h * NB + b] = rs;
        float fi = sigf(di * acc0[bi] + gb) * (di * acc1[bi] + mb);
        hin[h * NB + b] = rs + fi + cnt * kb;
      }
    }
  } else if (mode == 1) {
    int h = mT * 16 + tm;
    if (h < NH) {
#pragma unroll
      for (int bi = 0; bi < 4; ++bi) {
        int b = nB0 + tb * 4 + bi;
        PcO[h * NB + b] = acc0[bi];
        QcO[h * NB + b] = acc1[bi];
      }
    }
  } else {
    int m0 = mT * 32 + tm * 2;
#pragma unroll
    for (int bi = 0; bi < 4; ++bi) {
      int b = nB0 + tb * 4 + bi;
      if (m0 < NH2) { float v = acc0[bi] + av_b1[m0]; t1o[m0 * NB + b] = v > 0.f ? v : 0.f; }
      if (m0 + 1 < NH2) { float v = acc1[bi] + av_b1[m0 + 1]; t1o[(m0 + 1) * NB + b] = v > 0.f ? v : 0.f; }
    }
  }
}

// kGemm3: gru_hh GEMM + GRU combine. 48 rows (16 r/z/n triples) x 64 cols per block.
__global__ __launch_bounds__(256) void kGemm3(
    const float* __restrict__ pack,
    const float* __restrict__ src, const float* __restrict__ hid, int hasHid,
    const float* __restrict__ gi, const float* __restrict__ b_hh,
    float* __restrict__ dst,
    _Float16* __restrict__ snapXe, _Float16* __restrict__ snapXr) {
  __shared__ float Ws[16][48];
  __shared__ float Xs[16][64];
  int t = threadIdx.x;
  int tb = t & 15, tm = t >> 4;
  int mT = blockIdx.x, nB0 = blockIdx.y * 64;
  bool wact = t < 192;
  const float* wsrc = pack + (size_t)(1024 + mT * 48 + (t >> 2)) * KP + (t & 3) * 4;
  const float* xsrc = src + (size_t)(t >> 4) * NB + nB0 + (t & 15) * 4;
  float4 wv = make_float4(0, 0, 0, 0), xv;
  if (wact) wv = *(const float4*)(wsrc);
  xv = *(const float4*)(xsrc);
  float acc[3][4] = {};
  for (int ch = 0; ch < 32; ++ch) {
    if (wact) {
      int r = t >> 2, kq = (t & 3) * 4;
      Ws[kq + 0][r] = wv.x; Ws[kq + 1][r] = wv.y; Ws[kq + 2][r] = wv.z; Ws[kq + 3][r] = wv.w;
    }
    *(float4*)&Xs[t >> 4][(t & 15) * 4] = xv;
    __syncthreads();
    if (ch + 1 < 32) {
      if (wact) wv = *(const float4*)(wsrc + (ch + 1) * 16);
      xv = *(const float4*)(xsrc + (size_t)(ch + 1) * 16 * NB);
    }
#pragma unroll
    for (int kk = 0; kk < 16; ++kk) {
      float w0 = Ws[kk][tm * 3], w1 = Ws[kk][tm * 3 + 1], w2 = Ws[kk][tm * 3 + 2];
      float x0 = Xs[kk][tb * 4], x1 = Xs[kk][tb * 4 + 1];
      float x2 = Xs[kk][tb * 4 + 2], x3 = Xs[kk][tb * 4 + 3];
#pragma unroll
      for (int bi = 0; bi < 4; ++bi) {
        float x = bi == 0 ? x0 : (bi == 1 ? x1 : (bi == 2 ? x2 : x3));
        acc[0][bi] += w0 * x; acc[1][bi] += w1 * x; acc[2][bi] += w2 * x;
      }
    }
    __syncthreads();
  }
  int h = mT * 16 + tm;
  if (h < NH) {
    float bh_r = b_hh[h], bh_z = b_hh[NH + h], bh_n = b_hh[2 * NH + h];
#pragma unroll
    for (int bi = 0; bi < 4; ++bi) {
      int b = nB0 + tb * 4 + bi;
      float ir = gi[h * NB + b];
      float iz = gi[(NH + h) * NB + b];
      float inn = gi[(2 * NH + h) * NB + b];
      float r = sigf(ir + acc[0][bi] + bh_r);
      float zz = sigf(iz + acc[1][bi] + bh_z);
      float n = tanhf(inn + r * (acc[2][bi] + bh_n));
      float hd = hasHid ? hid[h * NB + b] : 0.f;
      float v = (1.f - zz) * n + zz * hd;
      dst[h * NB + b] = v;
      if (snapXe) snapXe[(size_t)b * KP + h] = (_Float16)v;
      if (snapXr) snapXr[(size_t)b * KP + h] = (_Float16)v;
    }
  }
}

// ---------------- MFMA fp16 deferred kernels ----------------
// R[m][col] = sum_k Wr[m][k] * Xr[col][k]   (m<2048, col<2048), stored fp16
__global__ __launch_bounds__(256) void kR(const _Float16* __restrict__ Wr,
                                          const _Float16* __restrict__ Xr,
                                          _Float16* __restrict__ R) {
  int t = threadIdx.x;
  int w = t >> 6, l = t & 63;
  int quad = l >> 4, lan = l & 15;
  int mB = blockIdx.x * 64, nB0 = blockIdx.y * 64;
  const _Float16* Arow = Wr + (size_t)(mB + w * 16 + lan) * KP + quad * 8;
  const _Float16* Brow = Xr + (size_t)(nB0 + lan) * KP + quad * 8;
  f32x4 acc[4];
#pragma unroll
  for (int ns = 0; ns < 4; ++ns) acc[ns] = (f32x4){0.f, 0.f, 0.f, 0.f};
  for (int k0 = 0; k0 < KP; k0 += 32) {
    half8 a = *(const half8*)(Arow + k0);
#pragma unroll
    for (int ns = 0; ns < 4; ++ns) {
      half8 b = *(const half8*)(Brow + (size_t)ns * 16 * KP + k0);
      acc[ns] = __builtin_amdgcn_mfma_f32_16x16x32_f16(a, b, acc[ns], 0, 0, 0);
    }
  }
#pragma unroll
  for (int ns = 0; ns < 4; ++ns) {
#pragma unroll
    for (int reg = 0; reg < 4; ++reg) {
      int m = mB + w * 16 + quad * 4 + reg;
      int col = nB0 + ns * 16 + lan;
      R[(size_t)m * 2048 + col] = (_Float16)acc[ns][reg];
    }
  }
}

// deferred edges: D = Wl @ Xe^T ; epilogue relu(D + R_j + b1) . ae_w2 -> atomicAdd out0
__global__ __launch_bounds__(256) void kEdge(const _Float16* __restrict__ Wl,
                                             const _Float16* __restrict__ Xe,
                                             const _Float16* __restrict__ R,
                                             const float* __restrict__ ae_b1,
                                             const float* __restrict__ ae_w2,
                                             float* __restrict__ out0) {
  __shared__ float sh[16][64];
  int t = threadIdx.x;
  int w = t >> 6, l = t & 63;
  int quad = l >> 4, lan = l & 15;
  int mB = blockIdx.x * 64, nB0 = blockIdx.y * 64;
  // decode snapshot id -> (index, j); all 64 cols of this block share one s
  int s = nB0 >> 8;
  int index = 1, base = 0;
  while (s >= base + index) { base += index; index++; }
  int j = index - 1 - (s - base);
  const _Float16* Arow = Wl + (size_t)(mB + w * 16 + lan) * KP + quad * 8;
  const _Float16* Brow = Xe + (size_t)(nB0 + lan) * KP + quad * 8;
  f32x4 acc[4];
#pragma unroll
  for (int ns = 0; ns < 4; ++ns) acc[ns] = (f32x4){0.f, 0.f, 0.f, 0.f};
  for (int k0 = 0; k0 < KP; k0 += 32) {
    half8 a = *(const half8*)(Arow + k0);
#pragma unroll
    for (int ns = 0; ns < 4; ++ns) {
      half8 b = *(const half8*)(Brow + (size_t)ns * 16 * KP + k0);
      acc[ns] = __builtin_amdgcn_mfma_f32_16x16x32_f16(a, b, acc[ns], 0, 0, 0);
    }
  }
#pragma unroll
  for (int ns = 0; ns < 4; ++ns) {
    float sum = 0.f;
    int bcol = (nB0 + ns * 16 + lan) & 255;
#pragma unroll
    for (int reg = 0; reg < 4; ++reg) {
      int m = mB + w * 16 + quad * 4 + reg;
      if (m < NH4) {
        float v = acc[ns][reg] + (float)R[(size_t)m * 2048 + j * 256 + bcol] + ae_b1[m];
        if (v > 0.f) sum += v * ae_w2[m];
      }
    }
    sh[w * 4 + quad][ns * 16 + lan] = sum;
  }
  __syncthreads();
  if (t < 64) {
    float ssum = 0.f;
#pragma unroll
    for (int q = 0; q < 16; ++q) ssum += sh[q][t];
    int b = (nB0 + t) & 255;
    atomicAdd(out0 + b * 64 + index * 8 + j, ssum);
  }
}

// ---------------- host ----------------

extern "C" void kernel_launch(void* const* d_in, const int* in_sizes, int n_in,
                              void* d_out, int out_size, void* d_ws, size_t ws_size,
                              hipStream_t stream) {
  (void)in_sizes; (void)n_in; (void)out_size; (void)ws_size;
  const float* z      = (const float*)d_in[0];
  const float* dep    = (const float*)d_in[1];
  const float* ne     = (const float*)d_in[2];
  const float* lin1_w = (const float*)d_in[3];
  const float* lin1_b = (const float*)d_in[4];
  const float* av_w1  = (const float*)d_in[5];
  const float* av_b1  = (const float*)d_in[6];
  const float* av_w2  = (const float*)d_in[7];
  const float* av_b2  = (const float*)d_in[8];
  const float* ae_w1  = (const float*)d_in[9];
  const float* ae_b1  = (const float*)d_in[10];
  const float* ae_w2  = (const float*)d_in[11];
  const float* ae_b2  = (const float*)d_in[12];
  const float* gate_w = (const float*)d_in[13];
  const float* gate_b = (const float*)d_in[14];
  const float* map_w  = (const float*)d_in[15];
  const float* map_b  = (const float*)d_in[16];
  const float* w_ih   = (const float*)d_in[17];
  const float* w_hh   = (const float*)d_in[18];
  const float* b_ih   = (const float*)d_in[19];
  const float* b_hh   = (const float*)d_in[20];

  float* out0 = (float*)d_out;
  float* out1 = out0 + NB * NS * NS;

  float* wsf = (float*)d_ws;
  size_t off = 0;
  float* hvA = wsf + off; off += HVSZ;
  float* hvB = wsf + off; off += HVSZ;
  float* hin = wsf + off; off += HVSZ;
  float* gi  = wsf + off; off += (size_t)NH3 * NB;
  float* t1  = wsf + off; off += (size_t)NH2 * NB;
  float* pack = wsf + off; off += (size_t)3584 * KP;
  _Float16* Wl = (_Float16*)(wsf + off); off += (size_t)2048 * KP / 2;
  _Float16* Wr = (_Float16*)(wsf + off); off += (size_t)2048 * KP / 2;
  _Float16* Xe = (_Float16*)(wsf + off); off += (size_t)7168 * KP / 2;
  _Float16* Xr = (_Float16*)(wsf + off); off += (size_t)2048 * KP / 2;
  float* Pc = wsf + off; off += (size_t)NS * HB;
  float* Qc = wsf + off; off += (size_t)NS * HB;
  float* RS = wsf + off; off += HVSZ;
  _Float16* R = (_Float16*)Pc;   // deferred-phase alias over dead Pc/Qc/RS

  float* bufs[2] = {hvA, hvB};
  int cur = 0;
  auto sidOf = [](int idx, int jj) { return idx * (idx - 1) / 2 + (idx - 1 - jj); };

  // init
  kPackF<<<3584, 256, 0, stream>>>(gate_w, map_w, w_hh, av_w1, pack);
  kPackH<<<2048, 256, 0, stream>>>(ae_w1, Wl, Wr);
  {
    int n4 = (7168 + 2048) * KP / 2 / 4;   // zero Xe+Xr (contiguous)
    kZero4<<<(n4 + 255) / 256, 256, 0, stream>>>((float4*)Xe, n4);
  }
  kPadZ<<<33, 256, 0, stream>>>(hvA, hvB, hin);
  kInit0<<<64, 256, 0, stream>>>(out0, ae_b2);
  kLin1<<<NH, 256, 0, stream>>>(z, lin1_w, lin1_b, hvA);

  for (int index = 0; index < NS; ++index) {
    // logits from current graph_state
    kGemm2<<<dim3(32, 4), 256, 0, stream>>>(pack, 2560, bufs[cur], 2, index, 0,
        nullptr, nullptr, nullptr, nullptr, nullptr, nullptr, nullptr,
        nullptr, nullptr, t1, av_b1);
    kLog2<<<8, 256, 0, stream>>>(t1, av_w2, av_b2, out1, index);
    kGi<<<NH3 + NH, 256, 0, stream>>>(ne, w_ih, b_ih, gi, RS, index);
    // hv0
    if (index == 0) {
      kGemm3<<<dim3(32, 4), 256, 0, stream>>>(pack, bufs[cur], bufs[cur], 1,
          gi, b_hh, bufs[1 - cur], nullptr, Xr);
    } else {
      kB0<<<NH, 256, 0, stream>>>(gi, b_hh, bufs[1 - cur],
          Xe + (size_t)sidOf(index, index - 1) * 256 * KP);
    }
    cur ^= 1;
    for (int j = index - 1; j >= 0; --j) {
      if (j == index - 1) {
        kAsmLite<<<NH, 256, 0, stream>>>(Pc + (size_t)j * HB, Qc + (size_t)j * HB,
                                         gate_b, map_b, dep, RS, hin, index, j);
      } else {
        kGemm2<<<dim3(32, 4), 256, 0, stream>>>(pack, 0, bufs[cur], 0, index, j,
            dep, gate_b, map_b, Pc + (size_t)j * HB, Qc + (size_t)j * HB, RS, hin,
            nullptr, nullptr, nullptr, nullptr);
      }
      _Float16* sXe = (j > 0) ? (Xe + (size_t)sidOf(index, j - 1) * 256 * KP) : nullptr;
      _Float16* sXr = (j == 0) ? (Xr + (size_t)index * 256 * KP) : nullptr;
      kGemm3<<<dim3(32, 4), 256, 0, stream>>>(pack, hin, hin, 1, gi, b_hh,
                                              bufs[1 - cur], sXe, sXr);
      cur ^= 1;
    }
    // cache P/Q for finalized nhs[:,index]
    kGemm2<<<dim3(32, 4), 256, 0, stream>>>(pack, 0, bufs[cur], 1, index, 0,
        nullptr, nullptr, nullptr, nullptr, nullptr, nullptr, nullptr,
        Pc + (size_t)index * HB, Qc + (size_t)index * HB, nullptr, nullptr);
  }

  // deferred: R then all 28 edge batches
  kR<<<dim3(32, 32), 256, 0, stream>>>(Wr, Xr, R);
  kEdge<<<dim3(32, 112), 256, 0, stream>>>(Wl, Xe, R, ae_b1, ae_w2, out0);
}